// Round 8
// baseline (25.415 us; speedup 1.0000x reference)
//
#include <hip/hip_runtime.h>
#include <math.h>

#define NB   2
#define NSEQ 1024
#define DD   256
#define LUTN 2048   // intervals; LUTN+1 entries over corr in [-1,1]

#define BM 128
#define BN 64
#define MAGIC 0x5CA1AB1Eu

typedef _Float16 f16;
typedef _Float16 f16x8 __attribute__((ext_vector_type(8)));
typedef float f32x4 __attribute__((ext_vector_type(4)));

__device__ __forceinline__ float wrsum(float v) {
#pragma unroll
  for (int off = 32; off > 0; off >>= 1) v += __shfl_xor(v, off, 64);
  return v;
}

// Single fused kernel, NO LDS A/B staging: fragments load global->reg
// (L2-resident panels), f16 hi/lo split in-register, barrier-free K-loop
// with 2-deep register prefetch. 512 threads = 8 waves (2/SIMD) as 4x2
// grid of 32x32 wave tiles over a 128x64 block tile.
__global__ __launch_bounds__(512, 2) void fused_kernel(
    const float* __restrict__ fg, const float* __restrict__ sg,
    const float* __restrict__ w1, const float* __restrict__ b1,
    const float* __restrict__ w2, const float* __restrict__ b2,
    float* __restrict__ lut, unsigned* __restrict__ flags,
    float* __restrict__ out) {
  __shared__ float lut_s[LUTN + 1];
  __shared__ float mA[BM], rA[BM], mB[BN], rB[BN];

  const int t = threadIdx.x;
  const int lane = t & 63;
  const int w = t >> 6;                 // 0..7
  const int wr = w >> 1, wc = w & 1;    // wave tile 32x32 at (wr*32, wc*32)
  const int la = lane & 15;             // fragment row within 16
  const int kg = lane >> 4;             // k-slice group 0..3

  const int bid = blockIdx.x;
  const int x = bid & 7, k = bid >> 3;  // XCD decode
  const int panel = x + 8 * (k >> 4);   // 0..15
  const int bz  = panel >> 3;
  const int bm0 = (panel & 7) * BM;
  const int bn0 = (k & 15) * BN;

  const float* fb = fg + ((size_t)bz * NSEQ + bm0) * DD;
  const float* sb = sg + ((size_t)bz * NSEQ + bn0) * DD;

  // per-lane fragment base pointers (k-offset 8*kg within each 32-chunk)
  const float* pa0 = fb + (size_t)(wr * 32 + la) * DD + 8 * kg;
  const float* pa1 = pa0 + 16 * DD;
  const float* pb0 = sb + (size_t)(wc * 32 + la) * DD + 8 * kg;
  const float* pb1 = pb0 + 16 * DD;

  float4 L[2][8];   // 2-deep prefetch sets: {A0,A0',A1,A1',B0,B0',B1,B1'}
  auto ld = [&](float4 (&d)[8], int st) {
    const int off = st * 32;
    d[0] = *reinterpret_cast<const float4*>(pa0 + off);
    d[1] = *reinterpret_cast<const float4*>(pa0 + off + 4);
    d[2] = *reinterpret_cast<const float4*>(pa1 + off);
    d[3] = *reinterpret_cast<const float4*>(pa1 + off + 4);
    d[4] = *reinterpret_cast<const float4*>(pb0 + off);
    d[5] = *reinterpret_cast<const float4*>(pb0 + off + 4);
    d[6] = *reinterpret_cast<const float4*>(pb1 + off);
    d[7] = *reinterpret_cast<const float4*>(pb1 + off + 4);
  };

  float sA[2] = {0.f, 0.f}, qA[2] = {0.f, 0.f};
  float sB[2] = {0.f, 0.f}, qB[2] = {0.f, 0.f};
  f32x4 acc[2][2] = {};

  auto step = [&](float4 (&d)[8]) {
    f16x8 fh[4], fl[4];
#pragma unroll
    for (int f = 0; f < 4; ++f) {
      const float vals[8] = {d[2*f].x, d[2*f].y, d[2*f].z, d[2*f].w,
                             d[2*f+1].x, d[2*f+1].y, d[2*f+1].z, d[2*f+1].w};
      float sm = 0.f, sq = 0.f;
#pragma unroll
      for (int e = 0; e < 8; ++e) {
        sm += vals[e];
        sq = fmaf(vals[e], vals[e], sq);
        const f16 h = (f16)vals[e];
        fh[f][e] = h;
        fl[f][e] = (f16)(vals[e] - (float)h);
      }
      if (f < 2) { if (wc == 0) { sA[f] += sm; qA[f] += sq; } }
      else       { if (wr == 0) { sB[f-2] += sm; qB[f-2] += sq; } }
    }
#pragma unroll
    for (int i = 0; i < 2; ++i)
#pragma unroll
      for (int j = 0; j < 2; ++j) {
        acc[i][j] = __builtin_amdgcn_mfma_f32_16x16x32_f16(fh[i], fh[2+j], acc[i][j], 0, 0, 0);
        acc[i][j] = __builtin_amdgcn_mfma_f32_16x16x32_f16(fh[i], fl[2+j], acc[i][j], 0, 0, 0);
        acc[i][j] = __builtin_amdgcn_mfma_f32_16x16x32_f16(fl[i], fh[2+j], acc[i][j], 0, 0, 0);
      }
  };

  ld(L[0], 0);     // in flight under the LUT VALU work
  ld(L[1], 1);

  // ---- LUT slice (8 entries/block via 8 waves), fence-free broadcast. ----
  {
    const float w1a = w1[lane], b1a = b1[lane], w2a = w2[lane];
    const float w1b = w1[lane + 64], b1b = b1[lane + 64], w2b = w2[lane + 64];
    const float b2v = b2[0];
    int e = bid * 8 + w;
#pragma unroll
    for (int pass = 0; pass < 2; ++pass) {
      if (pass == 1) { if (bid == 0 && w == 0) e = LUTN; else break; }
      const float corr = -1.0f + (float)e * (2.0f / LUTN);
      const float a = expf(corr);
      const float x0 = fmaf(a, w1a, b1a);
      const float x1 = fmaf(a, w1b, b1b);
      const float g0 = 0.5f * x0 * (1.0f + erff(x0 * 0.70710678118654752f));
      const float g1 = 0.5f * x1 * (1.0f + erff(x1 * 0.70710678118654752f));
      float acc2 = fmaf(g1, w2b, g0 * w2a);
      acc2 = wrsum(acc2);
      if (lane == 0)
        __hip_atomic_store(&lut[e], acc2 + b2v, __ATOMIC_RELAXED, __HIP_MEMORY_SCOPE_AGENT);
    }
    asm volatile("s_waitcnt vmcnt(0)" ::: "memory");  // own lut stores complete
    __syncthreads();                                  // all waves drained
    if (t == 0)
      __hip_atomic_store(&flags[bid], MAGIC, __ATOMIC_RELAXED, __HIP_MEMORY_SCOPE_AGENT);
  }

  // ---- Barrier-free K-loop, 2-deep register prefetch. ----
#pragma unroll
  for (int st = 0; st < DD / 32; ++st) {
    step(L[st & 1]);
    if (st < DD / 32 - 2) ld(L[st & 1], st + 2);
  }

  // ---- Fold stats (reduce over the 4 kg-groups) and publish to LDS. ----
  auto red16 = [](float v) {
    v += __shfl_xor(v, 16, 64);
    v += __shfl_xor(v, 32, 64);
    return v;
  };
#pragma unroll
  for (int f = 0; f < 2; ++f) {
    sA[f] = red16(sA[f]); qA[f] = red16(qA[f]);
    sB[f] = red16(sB[f]); qB[f] = red16(qB[f]);
  }
  if (wc == 0 && lane < 16) {
#pragma unroll
    for (int f = 0; f < 2; ++f) {
      const int r = wr * 32 + 16 * f + lane;
      const float m = sA[f] * (1.0f / DD);
      mA[r] = m;
      rA[r] = 1.0f / fmaxf(sqrtf(fmaxf(qA[f] - (float)DD * m * m, 0.0f)), 1e-6f);
    }
  }
  if (wr == 0 && lane < 16) {
#pragma unroll
    for (int f = 0; f < 2; ++f) {
      const int c = wc * 32 + 16 * f + lane;
      const float m = sB[f] * (1.0f / DD);
      mB[c] = m;
      rB[c] = 1.0f / fmaxf(sqrtf(fmaxf(qB[f] - (float)DD * m * m, 0.0f)), 1e-6f);
    }
  }

  // ---- Wait for all LUT slices, stage LUT into LDS. ----
  while (__hip_atomic_load(&flags[t & 255], __ATOMIC_RELAXED, __HIP_MEMORY_SCOPE_AGENT) != MAGIC) {}
  __syncthreads();   // stats + spin complete for all waves
  for (int i = t; i <= LUTN; i += 512)
    lut_s[i] = __hip_atomic_load(&lut[i], __ATOMIC_RELAXED, __HIP_MEMORY_SCOPE_AGENT);
  __syncthreads();

  // ---- Epilogue: rank-1 centering correction -> corr -> LUT -> store. ----
  float msv[2], rsv[2];
#pragma unroll
  for (int j = 0; j < 2; ++j) {
    const int cl = wc * 32 + 16 * j + la;
    msv[j] = mB[cl];
    rsv[j] = rB[cl];
  }
#pragma unroll
  for (int i = 0; i < 2; ++i) {
#pragma unroll
    for (int rg = 0; rg < 4; ++rg) {
      const int rowl = wr * 32 + 16 * i + 4 * kg + rg;
      const float mfv = mA[rowl];
      const float rfv = rA[rowl];
#pragma unroll
      for (int j = 0; j < 2; ++j) {
        // cov_centered/16 = rawdot/16 - 16*mf*ms   (256/16 = 16)
        const float cov = acc[i][j][rg] * (1.0f / 16.0f) - 16.0f * mfv * msv[j];
        float corr = fminf(fmaxf(cov * rfv * rsv[j], -1.0f), 1.0f);
        const float tf = (corr + 1.0f) * (float)(LUTN / 2);
        int idx = (int)tf;
        idx = idx > (LUTN - 1) ? (LUTN - 1) : idx;
        const float fr = tf - (float)idx;
        const float lo = lut_s[idx], hi = lut_s[idx + 1];
        out[((size_t)bz * NSEQ + bm0 + rowl) * NSEQ + bn0 + wc * 32 + 16 * j + la]
            = fmaf(fr, hi - lo, lo);
      }
    }
  }
}

extern "C" void kernel_launch(void* const* d_in, const int* in_sizes, int n_in,
                              void* d_out, int out_size, void* d_ws, size_t ws_size,
                              hipStream_t stream) {
  const float* f  = (const float*)d_in[0];
  const float* s  = (const float*)d_in[1];
  const float* w1 = (const float*)d_in[2];
  const float* b1 = (const float*)d_in[3];
  const float* w2 = (const float*)d_in[4];
  const float* b2 = (const float*)d_in[5];
  float* out = (float*)d_out;

  char* ws = (char*)d_ws;
  float* lut = (float*)(ws);                 // LUTN+1 floats
  unsigned* flags = (unsigned*)(ws + 16384); // 256 flags

  fused_kernel<<<256, 512, 0, stream>>>(f, s, w1, b1, w2, b2, lut, flags, out);
}

// Round 9
// 15.611 us; speedup vs baseline: 1.6280x; 1.6280x over previous
//
#include <hip/hip_runtime.h>
#include <math.h>

#define NB   2
#define NSEQ 1024
#define DD   256
#define LUTN 2048   // intervals; LUTN+1 entries over corr in [-1,1]

#define BM 128
#define BN 64
#define MAGIC 0x5CA1AB1Eu

typedef _Float16 f16;
typedef _Float16 f16x8 __attribute__((ext_vector_type(8)));
typedef float f32x4 __attribute__((ext_vector_type(4)));

__device__ __forceinline__ float wrsum(float v) {
#pragma unroll
  for (int off = 32; off > 0; off >>= 1) v += __shfl_xor(v, off, 64);
  return v;
}

// Single fused kernel (R7 structure + 8 waves + no-drain K-loop barriers).
// LDS-staged 128x64 tile, f16 hi/lo split in-register during staging,
// 8 waves as 4x2 of 32x32 wave tiles, BK=32 double-buffered LDS with
// XOR slot swizzle. K-loop barriers are raw s_barrier preceded only by
// lgkmcnt(0): prefetch global loads stay in flight across barriers.
__global__ __launch_bounds__(512, 2) void fused_kernel(
    const float* __restrict__ fg, const float* __restrict__ sg,
    const float* __restrict__ w1, const float* __restrict__ b1,
    const float* __restrict__ w2, const float* __restrict__ b2,
    float* __restrict__ lut, unsigned* __restrict__ flags,
    float* __restrict__ out) {
  __shared__ __align__(16) f16 As[2][BM * 64];  // row*64: [hi slots 0-3 | lo 4-7], slot ^= row&7
  __shared__ __align__(16) f16 Bs[2][BN * 64];
  __shared__ float lut_s[LUTN + 1];
  __shared__ float mA[BM], rA[BM], mB[BN], rB[BN];

  const int t = threadIdx.x;
  const int lane = t & 63;
  const int w = t >> 6;                 // 0..7
  const int wr = w >> 1, wc = w & 1;    // wave tile 32x32 at (wr*32, wc*32)
  const int la = lane & 15;
  const int kg = lane >> 4;             // k-slot group 0..3

  const int bid = blockIdx.x;
  const int x = bid & 7, k = bid >> 3;  // XCD decode
  const int panel = x + 8 * (k >> 4);   // 0..15
  const int bz  = panel >> 3;
  const int bm0 = (panel & 7) * BM;
  const int bn0 = (k & 15) * BN;

  const float* fb = fg + ((size_t)bz * NSEQ + bm0) * DD;
  const float* sb = sg + ((size_t)bz * NSEQ + bn0) * DD;

  const int sr = t >> 2;                // A staging row 0..127 (B: 0..63 for t<256)
  const int so = t & 3;                 // octet within BK=32
  const bool doB = (t < 256);

  float4 A0[2], B0[2], A1[2], B1[2];    // two prefetch sets
  float sAa = 0.f, qAa = 0.f, sBa = 0.f, qBa = 0.f;

  auto ld = [&](float4 (&a)[2], float4 (&b)[2], int st) {
    const float* p = &fb[(size_t)sr * DD + st * 32 + so * 8];
    a[0] = *reinterpret_cast<const float4*>(p);
    a[1] = *reinterpret_cast<const float4*>(p + 4);
    if (doB) {
      const float* q = &sb[(size_t)sr * DD + st * 32 + so * 8];
      b[0] = *reinterpret_cast<const float4*>(q);
      b[1] = *reinterpret_cast<const float4*>(q + 4);
    }
  };

  auto split8 = [](const float4& u0, const float4& u1, f16x8& hv, f16x8& lv,
                   float& sm, float& sq) {
    const float vals[8] = {u0.x, u0.y, u0.z, u0.w, u1.x, u1.y, u1.z, u1.w};
#pragma unroll
    for (int e = 0; e < 8; ++e) {
      sm += vals[e];
      sq = fmaf(vals[e], vals[e], sq);
      const f16 h = (f16)vals[e];
      hv[e] = h;
      lv[e] = (f16)(vals[e] - (float)h);
    }
  };

  auto cvt_write = [&](float4 (&a)[2], float4 (&b)[2], int pbuf) {
    f16x8 hv, lv;
    split8(a[0], a[1], hv, lv, sAa, qAa);
    *reinterpret_cast<f16x8*>(&As[pbuf][sr * 64 + ((so ^ (sr & 7)) << 3)]) = hv;
    *reinterpret_cast<f16x8*>(&As[pbuf][sr * 64 + (((4 + so) ^ (sr & 7)) << 3)]) = lv;
    if (doB) {
      split8(b[0], b[1], hv, lv, sBa, qBa);
      *reinterpret_cast<f16x8*>(&Bs[pbuf][sr * 64 + ((so ^ (sr & 7)) << 3)]) = hv;
      *reinterpret_cast<f16x8*>(&Bs[pbuf][sr * 64 + (((4 + so) ^ (sr & 7)) << 3)]) = lv;
    }
  };

  f32x4 acc[2][2] = {};

  auto do_mfma = [&](int p) {
    f16x8 ah[2], al[2], bh[2], bl[2];
#pragma unroll
    for (int i = 0; i < 2; ++i) {
      const int r = wr * 32 + 16 * i + la;
      ah[i] = *reinterpret_cast<const f16x8*>(&As[p][r * 64 + ((kg ^ (r & 7)) << 3)]);
      al[i] = *reinterpret_cast<const f16x8*>(&As[p][r * 64 + (((4 + kg) ^ (r & 7)) << 3)]);
    }
#pragma unroll
    for (int j = 0; j < 2; ++j) {
      const int r = wc * 32 + 16 * j + la;
      bh[j] = *reinterpret_cast<const f16x8*>(&Bs[p][r * 64 + ((kg ^ (r & 7)) << 3)]);
      bl[j] = *reinterpret_cast<const f16x8*>(&Bs[p][r * 64 + (((4 + kg) ^ (r & 7)) << 3)]);
    }
#pragma unroll
    for (int i = 0; i < 2; ++i)
#pragma unroll
      for (int j = 0; j < 2; ++j) {
        acc[i][j] = __builtin_amdgcn_mfma_f32_16x16x32_f16(ah[i], bh[j], acc[i][j], 0, 0, 0);
        acc[i][j] = __builtin_amdgcn_mfma_f32_16x16x32_f16(ah[i], bl[j], acc[i][j], 0, 0, 0);
        acc[i][j] = __builtin_amdgcn_mfma_f32_16x16x32_f16(al[i], bh[j], acc[i][j], 0, 0, 0);
      }
  };

  ld(A0, B0, 0);   // tile 0 in flight under the LUT VALU work

  // ---- LUT slice (8 entries/block via 8 waves), fence-free broadcast. ----
  {
    const float w1a = w1[lane], b1a = b1[lane], w2a = w2[lane];
    const float w1b = w1[lane + 64], b1b = b1[lane + 64], w2b = w2[lane + 64];
    const float b2v = b2[0];
    int e = bid * 8 + w;
#pragma unroll
    for (int pass = 0; pass < 2; ++pass) {
      if (pass == 1) { if (bid == 0 && w == 0) e = LUTN; else break; }
      const float corr = -1.0f + (float)e * (2.0f / LUTN);
      const float a = expf(corr);
      const float x0 = fmaf(a, w1a, b1a);
      const float x1 = fmaf(a, w1b, b1b);
      const float g0 = 0.5f * x0 * (1.0f + erff(x0 * 0.70710678118654752f));
      const float g1 = 0.5f * x1 * (1.0f + erff(x1 * 0.70710678118654752f));
      float acc2 = fmaf(g1, w2b, g0 * w2a);
      acc2 = wrsum(acc2);
      if (lane == 0)
        __hip_atomic_store(&lut[e], acc2 + b2v, __ATOMIC_RELAXED, __HIP_MEMORY_SCOPE_AGENT);
    }
  }

  cvt_write(A0, B0, 0);                              // tile 0 -> buf 0
  asm volatile("s_waitcnt vmcnt(0)" ::: "memory");   // lut stores complete
  __syncthreads();                                   // buf0 ready, all waves drained
  if (t == 0)
    __hip_atomic_store(&flags[bid], MAGIC, __ATOMIC_RELAXED, __HIP_MEMORY_SCOPE_AGENT);

  ld(A0, B0, 1);
  ld(A1, B1, 2);

  // ---- K-loop: no-drain barriers; prefetch stays in flight. ----
#pragma unroll
  for (int st = 0; st < 8; ++st) {
    do_mfma(st & 1);
    if (st < 7) {
      if (st & 1) {
        cvt_write(A1, B1, (st + 1) & 1);
        if (st < 6) ld(A1, B1, st + 3);
      } else {
        cvt_write(A0, B0, (st + 1) & 1);
        if (st < 6) ld(A0, B0, st + 3);
      }
      asm volatile("s_waitcnt lgkmcnt(0)" ::: "memory");  // ds ops done; vmcnt NOT drained
      __builtin_amdgcn_s_barrier();
    }
  }

  // ---- Fold stats (4 octet-threads per row) and publish to LDS. ----
  auto red4 = [](float v) {
    v += __shfl_xor(v, 1, 64);
    v += __shfl_xor(v, 2, 64);
    return v;
  };
  sAa = red4(sAa); qAa = red4(qAa);
  if ((t & 3) == 0) {
    const float m = sAa * (1.0f / DD);
    mA[sr] = m;
    rA[sr] = 1.0f / fmaxf(sqrtf(fmaxf(qAa - (float)DD * m * m, 0.0f)), 1e-6f);
  }
  if (doB) {
    sBa = red4(sBa); qBa = red4(qBa);
    if ((t & 3) == 0) {
      const float m = sBa * (1.0f / DD);
      mB[sr] = m;
      rB[sr] = 1.0f / fmaxf(sqrtf(fmaxf(qBa - (float)DD * m * m, 0.0f)), 1e-6f);
    }
  }

  // ---- Wait for all LUT slices, stage LUT into LDS. ----
  if (t < 256)
    while (__hip_atomic_load(&flags[t], __ATOMIC_RELAXED, __HIP_MEMORY_SCOPE_AGENT) != MAGIC) {}
  __syncthreads();
  for (int i = t; i <= LUTN; i += 512)
    lut_s[i] = __hip_atomic_load(&lut[i], __ATOMIC_RELAXED, __HIP_MEMORY_SCOPE_AGENT);
  __syncthreads();

  // ---- Epilogue: rank-1 centering correction -> corr -> LUT -> store. ----
  float msv[2], rsv[2];
#pragma unroll
  for (int j = 0; j < 2; ++j) {
    const int cl = wc * 32 + 16 * j + la;
    msv[j] = mB[cl];
    rsv[j] = rB[cl];
  }
#pragma unroll
  for (int i = 0; i < 2; ++i) {
#pragma unroll
    for (int rg = 0; rg < 4; ++rg) {
      const int rowl = wr * 32 + 16 * i + 4 * kg + rg;
      const float mfv = mA[rowl];
      const float rfv = rA[rowl];
#pragma unroll
      for (int j = 0; j < 2; ++j) {
        // cov_centered/16 = rawdot/16 - 16*mf*ms   (256/16 = 16)
        const float cov = acc[i][j][rg] * (1.0f / 16.0f) - 16.0f * mfv * msv[j];
        float corr = fminf(fmaxf(cov * rfv * rsv[j], -1.0f), 1.0f);
        const float tf = (corr + 1.0f) * (float)(LUTN / 2);
        int idx = (int)tf;
        idx = idx > (LUTN - 1) ? (LUTN - 1) : idx;
        const float fr = tf - (float)idx;
        const float lo = lut_s[idx], hi = lut_s[idx + 1];
        out[((size_t)bz * NSEQ + bm0 + rowl) * NSEQ + bn0 + wc * 32 + 16 * j + la]
            = fmaf(fr, hi - lo, lo);
      }
    }
  }
}

extern "C" void kernel_launch(void* const* d_in, const int* in_sizes, int n_in,
                              void* d_out, int out_size, void* d_ws, size_t ws_size,
                              hipStream_t stream) {
  const float* f  = (const float*)d_in[0];
  const float* s  = (const float*)d_in[1];
  const float* w1 = (const float*)d_in[2];
  const float* b1 = (const float*)d_in[3];
  const float* w2 = (const float*)d_in[4];
  const float* b2 = (const float*)d_in[5];
  float* out = (float*)d_out;

  char* ws = (char*)d_ws;
  float* lut = (float*)(ws);                 // LUTN+1 floats
  unsigned* flags = (unsigned*)(ws + 16384); // 256 flags

  fused_kernel<<<256, 512, 0, stream>>>(f, s, w1, b1, w2, b2, lut, flags, out);
}

// Round 10
// 14.906 us; speedup vs baseline: 1.7050x; 1.0473x over previous
//
#include <hip/hip_runtime.h>
#include <math.h>

#define NB   2
#define NSEQ 1024
#define DD   256
#define LUTN 2048   // intervals; LUTN+1 entries over corr in [-1,1]

#define BM 128
#define BN 64
#define MAGIC 0x5CA1AB1Eu

typedef _Float16 f16;
typedef _Float16 f16x8 __attribute__((ext_vector_type(8)));
typedef float f32x4 __attribute__((ext_vector_type(4)));

__device__ __forceinline__ float wrsum(float v) {
#pragma unroll
  for (int off = 32; off > 0; off >>= 1) v += __shfl_xor(v, off, 64);
  return v;
}

// Single fused kernel. BK=64 (two R9-style 32-f16 chunks per K-step), 4 K-steps,
// no-drain s_barriers, 2-set register prefetch, f16 hi/lo split in-register,
// stats folded during staging, fence-free LUT broadcast with mid-loop spin+stage.
__global__ __launch_bounds__(512, 1) void fused_kernel(
    const float* __restrict__ fg, const float* __restrict__ sg,
    const float* __restrict__ w1, const float* __restrict__ b1,
    const float* __restrict__ w2, const float* __restrict__ b2,
    float* __restrict__ lut, unsigned* __restrict__ flags,
    float* __restrict__ out) {
  __shared__ __align__(16) f16 As[2][2][BM * 64];  // [buf][chunk][row*64 + slot*8], slot ^= row&7
  __shared__ __align__(16) f16 Bs[2][2][BN * 64];
  __shared__ float lut_s[LUTN + 1];
  __shared__ float mA[BM], rA[BM], mB[BN], rB[BN];

  const int t = threadIdx.x;
  const int lane = t & 63;
  const int w = t >> 6;                 // 0..7
  const int wr = w >> 1, wc = w & 1;    // wave tile 32x32 at (wr*32, wc*32)
  const int la = lane & 15;
  const int kg = lane >> 4;             // k-slot group 0..3

  const int bid = blockIdx.x;
  const int x = bid & 7, k = bid >> 3;  // XCD decode
  const int panel = x + 8 * (k >> 4);   // 0..15
  const int bz  = panel >> 3;
  const int bm0 = (panel & 7) * BM;
  const int bn0 = (k & 15) * BN;

  const float* fb = fg + ((size_t)bz * NSEQ + bm0) * DD;
  const float* sb = sg + ((size_t)bz * NSEQ + bn0) * DD;

  // A staging: row t>>2 (0..127), octet t&3, both chunks.
  // B staging: row t>>3 (0..63), chunk (t>>2)&1, octet t&3.
  const int ar = t >> 2, ao = t & 3;
  const int br = t >> 3, bc = (t >> 2) & 1, bo = t & 3;

  float4 A0[4], B0[2], A1[4], B1[2];    // two prefetch sets
  float sAa = 0.f, qAa = 0.f, sBa = 0.f, qBa = 0.f;

  auto ld = [&](float4 (&a)[4], float4 (&b)[2], int st) {
    const float* p = &fb[(size_t)ar * DD + st * 64 + ao * 8];
    a[0] = *reinterpret_cast<const float4*>(p);
    a[1] = *reinterpret_cast<const float4*>(p + 4);
    a[2] = *reinterpret_cast<const float4*>(p + 32);
    a[3] = *reinterpret_cast<const float4*>(p + 36);
    const float* q = &sb[(size_t)br * DD + st * 64 + bc * 32 + bo * 8];
    b[0] = *reinterpret_cast<const float4*>(q);
    b[1] = *reinterpret_cast<const float4*>(q + 4);
  };

  auto split8 = [](const float4& u0, const float4& u1, f16x8& hv, f16x8& lv,
                   float& sm, float& sq) {
    const float vals[8] = {u0.x, u0.y, u0.z, u0.w, u1.x, u1.y, u1.z, u1.w};
#pragma unroll
    for (int e = 0; e < 8; ++e) {
      sm += vals[e];
      sq = fmaf(vals[e], vals[e], sq);
      const f16 h = (f16)vals[e];
      hv[e] = h;
      lv[e] = (f16)(vals[e] - (float)h);
    }
  };

  auto cvt_write = [&](float4 (&a)[4], float4 (&b)[2], int pbuf) {
#pragma unroll
    for (int ch = 0; ch < 2; ++ch) {
      f16x8 hv, lv;
      split8(a[2 * ch], a[2 * ch + 1], hv, lv, sAa, qAa);
      f16* base = &As[pbuf][ch][ar * 64];
      *reinterpret_cast<f16x8*>(&base[(ao ^ (ar & 7)) << 3]) = hv;
      *reinterpret_cast<f16x8*>(&base[((4 + ao) ^ (ar & 7)) << 3]) = lv;
    }
    {
      f16x8 hv, lv;
      split8(b[0], b[1], hv, lv, sBa, qBa);
      f16* base = &Bs[pbuf][bc][br * 64];
      *reinterpret_cast<f16x8*>(&base[(bo ^ (br & 7)) << 3]) = hv;
      *reinterpret_cast<f16x8*>(&base[((4 + bo) ^ (br & 7)) << 3]) = lv;
    }
  };

  f32x4 acc[2][2] = {};

  auto do_mfma = [&](int p) {
#pragma unroll
    for (int ks = 0; ks < 2; ++ks) {
      f16x8 ah[2], al[2], bh[2], bl[2];
#pragma unroll
      for (int i = 0; i < 2; ++i) {
        const int r = wr * 32 + 16 * i + la;
        const f16* base = &As[p][ks][r * 64];
        ah[i] = *reinterpret_cast<const f16x8*>(&base[(kg ^ (r & 7)) << 3]);
        al[i] = *reinterpret_cast<const f16x8*>(&base[((4 + kg) ^ (r & 7)) << 3]);
      }
#pragma unroll
      for (int j = 0; j < 2; ++j) {
        const int r = wc * 32 + 16 * j + la;
        const f16* base = &Bs[p][ks][r * 64];
        bh[j] = *reinterpret_cast<const f16x8*>(&base[(kg ^ (r & 7)) << 3]);
        bl[j] = *reinterpret_cast<const f16x8*>(&base[((4 + kg) ^ (r & 7)) << 3]);
      }
#pragma unroll
      for (int i = 0; i < 2; ++i)
#pragma unroll
        for (int j = 0; j < 2; ++j) {
          acc[i][j] = __builtin_amdgcn_mfma_f32_16x16x32_f16(ah[i], bh[j], acc[i][j], 0, 0, 0);
          acc[i][j] = __builtin_amdgcn_mfma_f32_16x16x32_f16(ah[i], bl[j], acc[i][j], 0, 0, 0);
          acc[i][j] = __builtin_amdgcn_mfma_f32_16x16x32_f16(al[i], bh[j], acc[i][j], 0, 0, 0);
        }
    }
  };

  ld(A0, B0, 0);   // tile 0 in flight under the LUT VALU work

  // ---- LUT slice (8 entries/block via 8 waves), fence-free broadcast. ----
  {
    const float w1a = w1[lane], b1a = b1[lane], w2a = w2[lane];
    const float w1b = w1[lane + 64], b1b = b1[lane + 64], w2b = w2[lane + 64];
    const float b2v = b2[0];
    int e = bid * 8 + w;
#pragma unroll
    for (int pass = 0; pass < 2; ++pass) {
      if (pass == 1) { if (bid == 0 && w == 0) e = LUTN; else break; }
      const float corr = -1.0f + (float)e * (2.0f / LUTN);
      const float a = expf(corr);
      const float x0 = fmaf(a, w1a, b1a);
      const float x1 = fmaf(a, w1b, b1b);
      const float g0 = 0.5f * x0 * (1.0f + erff(x0 * 0.70710678118654752f));
      const float g1 = 0.5f * x1 * (1.0f + erff(x1 * 0.70710678118654752f));
      float acc2 = fmaf(g1, w2b, g0 * w2a);
      acc2 = wrsum(acc2);
      if (lane == 0)
        __hip_atomic_store(&lut[e], acc2 + b2v, __ATOMIC_RELAXED, __HIP_MEMORY_SCOPE_AGENT);
    }
  }

  cvt_write(A0, B0, 0);                              // tile 0 -> buf 0
  asm volatile("s_waitcnt vmcnt(0)" ::: "memory");   // lut stores complete
  __syncthreads();                                   // buf0 ready, all waves drained
  if (t == 0)
    __hip_atomic_store(&flags[bid], MAGIC, __ATOMIC_RELAXED, __HIP_MEMORY_SCOPE_AGENT);

  ld(A0, B0, 1);
  ld(A1, B1, 2);

  // ---- 4-step K-loop (BK=64), no-drain barriers. ----
  // step 0
  do_mfma(0);
  cvt_write(A0, B0, 1);
  ld(A0, B0, 3);
  asm volatile("s_waitcnt lgkmcnt(0)" ::: "memory");
  __builtin_amdgcn_s_barrier();
  // step 1
  do_mfma(1);
  cvt_write(A1, B1, 0);
  asm volatile("s_waitcnt lgkmcnt(0)" ::: "memory");
  __builtin_amdgcn_s_barrier();
  // step 2 (+ mid-loop LUT spin & stage: no prefetches left outstanding)
  do_mfma(0);
  cvt_write(A0, B0, 1);
  if (t < 256)
    while (__hip_atomic_load(&flags[t], __ATOMIC_RELAXED, __HIP_MEMORY_SCOPE_AGENT) != MAGIC) {}
#pragma unroll
  for (int i = t; i <= LUTN; i += 512)
    lut_s[i] = __hip_atomic_load(&lut[i], __ATOMIC_RELAXED, __HIP_MEMORY_SCOPE_AGENT);
  asm volatile("s_waitcnt lgkmcnt(0)" ::: "memory");
  __builtin_amdgcn_s_barrier();
  // step 3
  do_mfma(1);

  // ---- Fold stats and publish to LDS. ----
  auto red4 = [](float v) {
    v += __shfl_xor(v, 1, 64);
    v += __shfl_xor(v, 2, 64);
    return v;
  };
  sAa = red4(sAa); qAa = red4(qAa);
  if ((t & 3) == 0) {
    const float m = sAa * (1.0f / DD);
    mA[ar] = m;
    rA[ar] = 1.0f / fmaxf(sqrtf(fmaxf(qAa - (float)DD * m * m, 0.0f)), 1e-6f);
  }
  sBa = red4(sBa); sBa += __shfl_xor(sBa, 4, 64);
  qBa = red4(qBa); qBa += __shfl_xor(qBa, 4, 64);
  if ((t & 7) == 0) {
    const float m = sBa * (1.0f / DD);
    mB[br] = m;
    rB[br] = 1.0f / fmaxf(sqrtf(fmaxf(qBa - (float)DD * m * m, 0.0f)), 1e-6f);
  }
  __syncthreads();   // stats + lut_s visible to all

  // ---- Epilogue: rank-1 centering correction -> corr -> LUT -> store. ----
  float msv[2], rsv[2];
#pragma unroll
  for (int j = 0; j < 2; ++j) {
    const int cl = wc * 32 + 16 * j + la;
    msv[j] = mB[cl];
    rsv[j] = rB[cl];
  }
#pragma unroll
  for (int i = 0; i < 2; ++i) {
#pragma unroll
    for (int rg = 0; rg < 4; ++rg) {
      const int rowl = wr * 32 + 16 * i + 4 * kg + rg;
      const float mfv = mA[rowl];
      const float rfv = rA[rowl];
#pragma unroll
      for (int j = 0; j < 2; ++j) {
        // cov_centered/16 = rawdot/16 - 16*mf*ms   (256/16 = 16)
        const float cov = acc[i][j][rg] * (1.0f / 16.0f) - 16.0f * mfv * msv[j];
        float corr = fminf(fmaxf(cov * rfv * rsv[j], -1.0f), 1.0f);
        const float tf = (corr + 1.0f) * (float)(LUTN / 2);
        int idx = (int)tf;
        idx = idx > (LUTN - 1) ? (LUTN - 1) : idx;
        const float fr = tf - (float)idx;
        const float lo = lut_s[idx], hi = lut_s[idx + 1];
        out[((size_t)bz * NSEQ + bm0 + rowl) * NSEQ + bn0 + wc * 32 + 16 * j + la]
            = fmaf(fr, hi - lo, lo);
      }
    }
  }
}

extern "C" void kernel_launch(void* const* d_in, const int* in_sizes, int n_in,
                              void* d_out, int out_size, void* d_ws, size_t ws_size,
                              hipStream_t stream) {
  const float* f  = (const float*)d_in[0];
  const float* s  = (const float*)d_in[1];
  const float* w1 = (const float*)d_in[2];
  const float* b1 = (const float*)d_in[3];
  const float* w2 = (const float*)d_in[4];
  const float* b2 = (const float*)d_in[5];
  float* out = (float*)d_out;

  char* ws = (char*)d_ws;
  float* lut = (float*)(ws);                 // LUTN+1 floats
  unsigned* flags = (unsigned*)(ws + 16384); // 256 flags

  fused_kernel<<<256, 512, 0, stream>>>(f, s, w1, b1, w2, b2, lut, flags, out);
}